// Round 9
// baseline (499.534 us; speedup 1.0000x reference)
//
#include <hip/hip_runtime.h>

// ---------------------------------------------------------------------------
// SegFormerXAttention on MI355X (gfx950)
//  B=4, Lv=1024, Lt=256, D=1024, H=16, DH=64, L=1280. fp32 in/out, int32 masks.
//  r9 == r8 with the legacy MFMA intrinsic spelling fixed:
//  __builtin_amdgcn_mfma_f32_16x16x16f16 (no underscore; half4 operands).
//  r8: attention computes S^T (swap QK^T MFMA operands: A=K, B=Q) so each
//      lane owns ONE query (col) and 4 keys (rows). Online-softmax state is
//      scalar/lane; row-max merge = 2 shuffle rounds; exp'd P stays in
//      registers in exactly the B-operand layout of the 16x16x16 f16 MFMA
//      -> PV needs NO LDS round-trip. LDS only for the split-K merge.
// ---------------------------------------------------------------------------

typedef __attribute__((ext_vector_type(8))) _Float16  half8;    // 8 x f16
typedef __attribute__((ext_vector_type(4))) _Float16  half4;    // 4 x f16
typedef __attribute__((ext_vector_type(4))) float     f32x4;
typedef __attribute__((ext_vector_type(4))) unsigned int uint4v;

#define MFMA_F16   __builtin_amdgcn_mfma_f32_16x16x32_f16
#define MFMA16_F16 __builtin_amdgcn_mfma_f32_16x16x16f16

static __device__ __forceinline__ unsigned short f_to_f16u(float f) {
  _Float16 h = (_Float16)f;
  return __builtin_bit_cast(unsigned short, h);
}

#define GLOAD_LDS16(g, l)                                            \
  __builtin_amdgcn_global_load_lds(                                  \
      (const __attribute__((address_space(1))) void*)(g),            \
      (__attribute__((address_space(3))) void*)(l), 16, 0, 0)

// ---------------------------------------------------------------------------
// Pre-pass: fp32 -> fp16 elementwise
// ---------------------------------------------------------------------------
struct CvtDesc { const float* src; unsigned short* dst; int n8; };
struct CvtArgs { CvtDesc d[14]; };

__global__ __launch_bounds__(256) void cvt_fp16(CvtArgs ca) {
  const CvtDesc dd = ca.d[blockIdx.y];
  const int stride = gridDim.x * blockDim.x;
  for (int i = blockIdx.x * blockDim.x + threadIdx.x; i < dd.n8; i += stride) {
    const f32x4 a = ((const f32x4*)dd.src)[i * 2];
    const f32x4 b = ((const f32x4*)dd.src)[i * 2 + 1];
    half8 h;
    h[0] = (_Float16)a[0]; h[1] = (_Float16)a[1];
    h[2] = (_Float16)a[2]; h[3] = (_Float16)a[3];
    h[4] = (_Float16)b[0]; h[5] = (_Float16)b[1];
    h[6] = (_Float16)b[2]; h[7] = (_Float16)b[3];
    ((half8*)dd.dst)[i] = h;
  }
}

// key-mask bias: kb[b][k] = mask ? 0 : -10000  (reuses dead Xv_h region)
__global__ __launch_bounds__(256) void make_kbias(
    const int* __restrict__ vmask, const int* __restrict__ tmask,
    float* __restrict__ kb) {
  const int b = blockIdx.y;
  const int k = blockIdx.x * 256 + threadIdx.x;
  if (k >= 1280) return;
  const int m = (k < 1024) ? vmask[b * 1024 + k] : tmask[b * 256 + k - 1024];
  kb[b * 1280 + k] = m ? 0.0f : -10000.0f;
}

// ---------------------------------------------------------------------------
// Projection GEMM (fp16 inputs) -- unchanged from r7
// ---------------------------------------------------------------------------
struct ProjDescH {
  const unsigned short* X;
  const unsigned short* W;
  const float* Bv;
  unsigned short* dst;
  int M, lxsh, Ld, soff, mode;
};
struct ProjArgsH { ProjDescH d[12]; };

__global__ __launch_bounds__(256) void proj_gemm_h(ProjArgsH pa) {
  const ProjDescH dd = pa.d[blockIdx.z];
  const int m0 = blockIdx.y * 128;
  if (m0 >= dd.M) return;
  const int n0 = blockIdx.x * 128;

  __shared__ __align__(16) unsigned char smem[34816];
  unsigned short* As = (unsigned short*)smem;
  unsigned short* Bs = As + 4096;
  unsigned short* Cs = (unsigned short*)smem;

  const int tid  = threadIdx.x;
  const int lane = tid & 63;
  const int w    = tid >> 6;
  const int wr   = (w >> 1) * 64;
  const int wc   = (w & 1) * 64;
  const int ql   = lane & 15;
  const int qd   = lane >> 4;

  f32x4 acc[4][4];
  for (int i = 0; i < 4; ++i)
    for (int j = 0; j < 4; ++j) acc[i][j] = (f32x4)(0.0f);

  const unsigned short* Xg = dd.X + (size_t)m0 * 1024;
  const unsigned short* Wg = dd.W + (size_t)n0 * 1024;

  for (int k0 = 0; k0 < 1024; k0 += 32) {
    __syncthreads();
    for (int half = 0; half < 2; ++half) {
      const int cb  = w * 128 + half * 64;
      const int c   = cb + lane;
      const int row = c >> 2;
      const int kcg = (c & 3) ^ (row & 3);
      GLOAD_LDS16(Xg + row * 1024 + k0 + kcg * 8, As + cb * 8);
      GLOAD_LDS16(Wg + row * 1024 + k0 + kcg * 8, Bs + cb * 8);
    }
    __syncthreads();

    half8 af[4], bf[4];
    for (int mt = 0; mt < 4; ++mt) {
      const int row = wr + mt * 16 + ql;
      af[mt] = *(const half8*)&As[row * 32 + ((qd ^ (row & 3)) << 3)];
    }
    for (int nt = 0; nt < 4; ++nt) {
      const int row = wc + nt * 16 + ql;
      bf[nt] = *(const half8*)&Bs[row * 32 + ((qd ^ (row & 3)) << 3)];
    }
    for (int mt = 0; mt < 4; ++mt)
      for (int nt = 0; nt < 4; ++nt)
        acc[mt][nt] = MFMA_F16(af[mt], bf[nt], acc[mt][nt], 0, 0, 0);
  }

  float bv[4];
  for (int nt = 0; nt < 4; ++nt)
    bv[nt] = dd.Bv[n0 + wc + nt * 16 + ql];

  __syncthreads();

  for (int mt = 0; mt < 4; ++mt) {
    for (int nt = 0; nt < 4; ++nt) {
      const int nl = wc + nt * 16 + ql;
      for (int r = 0; r < 4; ++r) {
        const int ml = wr + mt * 16 + qd * 4 + r;
        const int row = dd.mode == 0 ? ml : nl;
        const int col = dd.mode == 0 ? nl : ml;
        const float v = acc[mt][nt][r] + bv[nt];
        Cs[row * 136 + (((col >> 3) ^ (row & 7)) << 3) + (col & 7)] = f_to_f16u(v);
      }
    }
  }
  __syncthreads();

  const int b    = m0 >> dd.lxsh;
  const int l0   = m0 & ((1 << dd.lxsh) - 1);
  const int h0   = n0 >> 6;
  const int bh0  = b * 16 + h0;
  for (int i = 0; i < 8; ++i) {
    const int c     = i * 256 + tid;
    const int major = c >> 4;
    const int kc    = c & 15;
    const uint4v val =
        *(const uint4v*)&Cs[major * 136 + ((kc ^ (major & 7)) << 3)];
    size_t el;
    if (dd.mode == 0) {
      el = ((size_t)(bh0 + (kc >> 3)) * dd.Ld + dd.soff + l0 + major) * 64 +
           (kc & 7) * 8;
    } else {
      const int h  = h0 + (major >> 6);
      const int dh = major & 63;
      el = ((size_t)(b * 16 + h) * 64 + dh) * (size_t)dd.Ld + dd.soff + l0 + kc * 8;
    }
    *(uint4v*)(dd.dst + el) = val;
  }
}

// ---------------------------------------------------------------------------
// Fallback fp32-input GEMM (r5 version) for small ws_size
// ---------------------------------------------------------------------------
struct ProjDesc {
  const float* X;
  const float* W;
  const float* Bv;
  unsigned short* dst;
  int M, lxsh, Ld, soff, mode;
};
struct ProjArgs { ProjDesc d[12]; };

static __device__ __forceinline__ half8 cvt8sw(const float* base, int row, int g0) {
  const int sw = row & 7;
  const f32x4 a = *(const f32x4*)(base + (row * 8 + (g0 ^ sw)) * 4);
  const f32x4 b = *(const f32x4*)(base + (row * 8 + ((g0 + 1) ^ sw)) * 4);
  half8 h;
  h[0] = (_Float16)a[0]; h[1] = (_Float16)a[1];
  h[2] = (_Float16)a[2]; h[3] = (_Float16)a[3];
  h[4] = (_Float16)b[0]; h[5] = (_Float16)b[1];
  h[6] = (_Float16)b[2]; h[7] = (_Float16)b[3];
  return h;
}

__global__ __launch_bounds__(256) void proj_gemm_f32(ProjArgs pa) {
  const ProjDesc dd = pa.d[blockIdx.z];
  const int m0 = blockIdx.y * 128;
  if (m0 >= dd.M) return;
  const int n0 = blockIdx.x * 128;

  __shared__ __align__(16) unsigned char smem[34816];
  float* As = (float*)smem;
  float* Bs = As + 4096;
  unsigned short* Cs = (unsigned short*)smem;

  const int tid  = threadIdx.x;
  const int lane = tid & 63;
  const int w    = tid >> 6;
  const int wr   = (w >> 1) * 64;
  const int wc   = (w & 1) * 64;
  const int ql   = lane & 15;
  const int qd   = lane >> 4;

  f32x4 acc[4][4];
  for (int i = 0; i < 4; ++i)
    for (int j = 0; j < 4; ++j) acc[i][j] = (f32x4)(0.0f);

  const float* Xg = dd.X + (size_t)m0 * 1024;
  const float* Wg = dd.W + (size_t)n0 * 1024;

  for (int k0 = 0; k0 < 1024; k0 += 32) {
    __syncthreads();
    for (int j = 0; j < 4; ++j) {
      const int cb  = (j * 4 + w) * 64;
      const int c   = cb + lane;
      const int row = c >> 3;
      const int kcg = (c & 7) ^ (row & 7);
      GLOAD_LDS16(Xg + row * 1024 + k0 + kcg * 4, As + cb * 4);
      GLOAD_LDS16(Wg + row * 1024 + k0 + kcg * 4, Bs + cb * 4);
    }
    __syncthreads();

    half8 af[4], bf[4];
    for (int mt = 0; mt < 4; ++mt)
      af[mt] = cvt8sw(As, wr + mt * 16 + ql, qd * 2);
    for (int nt = 0; nt < 4; ++nt)
      bf[nt] = cvt8sw(Bs, wc + nt * 16 + ql, qd * 2);
    for (int mt = 0; mt < 4; ++mt)
      for (int nt = 0; nt < 4; ++nt)
        acc[mt][nt] = MFMA_F16(af[mt], bf[nt], acc[mt][nt], 0, 0, 0);
  }

  float bv[4];
  for (int nt = 0; nt < 4; ++nt)
    bv[nt] = dd.Bv[n0 + wc + nt * 16 + ql];

  __syncthreads();

  for (int mt = 0; mt < 4; ++mt) {
    for (int nt = 0; nt < 4; ++nt) {
      const int nl = wc + nt * 16 + ql;
      for (int r = 0; r < 4; ++r) {
        const int ml = wr + mt * 16 + qd * 4 + r;
        const int row = dd.mode == 0 ? ml : nl;
        const int col = dd.mode == 0 ? nl : ml;
        const float v = acc[mt][nt][r] + bv[nt];
        Cs[row * 136 + (((col >> 3) ^ (row & 7)) << 3) + (col & 7)] = f_to_f16u(v);
      }
    }
  }
  __syncthreads();

  const int b    = m0 >> dd.lxsh;
  const int l0   = m0 & ((1 << dd.lxsh) - 1);
  const int h0   = n0 >> 6;
  const int bh0  = b * 16 + h0;
  for (int i = 0; i < 8; ++i) {
    const int c     = i * 256 + tid;
    const int major = c >> 4;
    const int kc    = c & 15;
    const uint4v val =
        *(const uint4v*)&Cs[major * 136 + ((kc ^ (major & 7)) << 3)];
    size_t el;
    if (dd.mode == 0) {
      el = ((size_t)(bh0 + (kc >> 3)) * dd.Ld + dd.soff + l0 + major) * 64 +
           (kc & 7) * 8;
    } else {
      const int h  = h0 + (major >> 6);
      const int dh = major & 63;
      el = ((size_t)(b * 16 + h) * 64 + dh) * (size_t)dd.Ld + dd.soff + l0 + kc * 8;
    }
    *(uint4v*)(dd.dst + el) = val;
  }
}

// ---------------------------------------------------------------------------
// Split-K flash attention, S^T form. Block = 16 q-rows (x<64: v, x>=64: t);
//  wave w covers keys [w*320, w*320+320). Per 16-key tile:
//   S^T = MFMA(A=K_frag, B=Q_frag, acc=kbias4)  -> lane owns query ql,
//   keys qd*4+r. Scalar m/l/alpha; max-merge = 2 shuffle rounds; exp'd P
//   packed to half4 = exactly the B operand of the 16x16x16 f16 MFMA for PV
//   against V^T b64 fragments. No LDS in the loop. End: 4-wave (m,l,o)
//   merge via LDS, out = 0.125 * o* / l*.
// ---------------------------------------------------------------------------
__global__ __launch_bounds__(256) void attn_flash4(
    const unsigned short* __restrict__ Qa_v, const unsigned short* __restrict__ Qb_v,
    const unsigned short* __restrict__ K_v,  const unsigned short* __restrict__ V_vT,
    const unsigned short* __restrict__ Qa_t, const unsigned short* __restrict__ Qb_t,
    const unsigned short* __restrict__ K_t,  const unsigned short* __restrict__ V_tT,
    const int* __restrict__ vmask, const int* __restrict__ tmask,
    const float* __restrict__ kbias,
    float* __restrict__ out_v, float* __restrict__ out_t) {
  __shared__ __align__(16) float oM[4 * 1088];   // o[w][q=ql][68] (17408 B)
  __shared__ float mlM[128];                     // ml[w][{m,l}][16]

  const bool vside = blockIdx.x < 64;
  const int  qb    = vside ? blockIdx.x : blockIdx.x - 64;
  const int  Lq    = vside ? 1024 : 256;
  const unsigned short* Qa = vside ? Qa_v : Qa_t;
  const unsigned short* Qb = vside ? Qb_v : Qb_t;
  const unsigned short* K  = vside ? K_v  : K_t;
  const unsigned short* VT = vside ? V_vT : V_tT;
  const int* mq  = vside ? vmask : tmask;
  float*     out = vside ? out_v : out_t;

  const int bh = blockIdx.y;
  const int b  = bh >> 4;
  const int h  = bh & 15;
  const int w    = threadIdx.x >> 6;
  const int lane = threadIdx.x & 63;
  const int ql = lane & 15, qd = lane >> 4;
  const int q0 = qb * 16;

  // Q fragments (B operand of S^T MFMA): lane holds Q[q0+ql][qd*8+j]
  const unsigned short* Qab = Qa + ((size_t)bh * Lq + q0) * 64;
  const unsigned short* Qbb = Qb + ((size_t)bh * Lq + q0) * 64;
  half8 aA[2], aB[2];
  for (int ks = 0; ks < 2; ++ks) {
    aA[ks] = *(const half8*)&Qab[ql * 64 + ks * 32 + qd * 8];
    aB[ks] = *(const half8*)&Qbb[ql * 64 + ks * 32 + qd * 8];
  }
  const int mqs = mq[b * Lq + q0 + ql];   // this lane's query mask

  float m = -1e30f, l = 0.0f;
  f32x4 o[4];
  for (int nt = 0; nt < 4; ++nt) o[nt] = (f32x4)(0.0f);

  const unsigned short* Kb = K  + (size_t)bh * 1280 * 64;
  const unsigned short* Vb = VT + (size_t)bh * 64 * 1280;
  const float* kbb = kbias + b * 1280;

  const int kw0 = w * 320;
  for (int k0 = kw0; k0 < kw0 + 320; k0 += 32) {
    const bool vidp = (k0 < 1024);
    f32x4 sv[2];
    for (int sub = 0; sub < 2; ++sub) {
      const int kb = k0 + sub * 16;
      // acc init = key-mask bias for this lane's 4 keys (aligned f32x4)
      f32x4 S = *(const f32x4*)&kbb[kb + qd * 4];
      const half8 kf0 = *(const half8*)&Kb[(kb + ql) * 64 + qd * 8];
      const half8 kf1 = *(const half8*)&Kb[(kb + ql) * 64 + 32 + qd * 8];
      if (vidp) { S = MFMA_F16(kf0, aA[0], S, 0, 0, 0); S = MFMA_F16(kf1, aA[1], S, 0, 0, 0); }
      else      { S = MFMA_F16(kf0, aB[0], S, 0, 0, 0); S = MFMA_F16(kf1, aB[1], S, 0, 0, 0); }
      for (int r = 0; r < 4; ++r)
        sv[sub][r] = mqs ? S[r] : -10000.0f;
    }
    // block max for query ql: local 8 + merge across the 4 qd lane-groups
    float bm = fmaxf(fmaxf(fmaxf(sv[0][0], sv[0][1]), fmaxf(sv[0][2], sv[0][3])),
                     fmaxf(fmaxf(sv[1][0], sv[1][1]), fmaxf(sv[1][2], sv[1][3])));
    bm = fmaxf(bm, __shfl_xor(bm, 16, 64));
    bm = fmaxf(bm, __shfl_xor(bm, 32, 64));
    const float nm = fmaxf(m, bm);
    const float alpha = __expf(m - nm);
    m = nm;
    half4 pv[2];
    float lsum = 0.0f;
    for (int sub = 0; sub < 2; ++sub)
      for (int r = 0; r < 4; ++r) {
        const float p = __expf(sv[sub][r] - m);   // arg <= 0 always
        lsum += p;
        pv[sub][r] = (_Float16)p;
      }
    l = l * alpha + lsum;
    for (int nt = 0; nt < 4; ++nt)
      for (int r = 0; r < 4; ++r) o[nt][r] *= alpha;

    // PV: O^T += V^T . P^T  via 16x16x16 (A = V^T 4-half frags, B = pv)
    for (int sub = 0; sub < 2; ++sub) {
      const int kb = k0 + sub * 16;
      for (int nt = 0; nt < 4; ++nt) {
        const half4 av = *(const half4*)&Vb[(nt * 16 + ql) * 1280 + kb + qd * 4];
        o[nt] = MFMA16_F16(av, pv[sub], o[nt], 0, 0, 0);
      }
    }
  }

  // total l for query ql within this wave's key range (m already shared)
  l += __shfl_xor(l, 16, 64);
  l += __shfl_xor(l, 32, 64);

  // split-K merge across the 4 waves
  for (int nt = 0; nt < 4; ++nt)
    for (int r = 0; r < 4; ++r)
      oM[w * 1088 + ql * 68 + nt * 16 + qd * 4 + r] = o[nt][r];
  if (qd == 0) {
    mlM[w * 32 + ql]      = m;
    mlM[w * 32 + 16 + ql] = l;
  }
  __syncthreads();

  const int q  = threadIdx.x >> 4;
  const int d0 = (threadIdx.x & 15) * 4;
  float mw[4], lw[4];
  for (int w2 = 0; w2 < 4; ++w2) {
    mw[w2] = mlM[w2 * 32 + q];
    lw[w2] = mlM[w2 * 32 + 16 + q];
  }
  float ms = fmaxf(fmaxf(mw[0], mw[1]), fmaxf(mw[2], mw[3]));
  float fw[4], ls = 0.0f;
  for (int w2 = 0; w2 < 4; ++w2) {
    fw[w2] = __expf(mw[w2] - ms);
    ls += fw[w2] * lw[w2];
  }
  const float inv = 0.125f / ls;   // ls >= 1 always
  f32x4 res;
  for (int j = 0; j < 4; ++j) {
    float a = 0.0f;
    for (int w2 = 0; w2 < 4; ++w2)
      a += fw[w2] * oM[w2 * 1088 + q * 68 + d0 + j];
    res[j] = a * inv;
  }
  *(f32x4*)(out + ((size_t)(b * Lq + q0 + q)) * 1024 + h * 64 + d0) = res;
}

// ---------------------------------------------------------------------------
extern "C" void kernel_launch(void* const* d_in, const int* in_sizes, int n_in,
                              void* d_out, int out_size, void* d_ws, size_t ws_size,
                              hipStream_t stream) {
  const float* vid   = (const float*)d_in[0];
  const int*   vmask = (const int*)d_in[1];
  const float* txt   = (const float*)d_in[2];
  const int*   tmask = (const int*)d_in[3];
  const float* Wsrc[4] = {(const float*)d_in[4], (const float*)d_in[6],
                          (const float*)d_in[8], (const float*)d_in[10]};
  const float* Bsrc[4] = {(const float*)d_in[5], (const float*)d_in[7],
                          (const float*)d_in[9], (const float*)d_in[11]};

  const int DD = 1024 * 1024, Dm = 1024, MEG = 1048576;

  unsigned short* ws = (unsigned short*)d_ws;
  unsigned short* Qa_v = ws;                       // 4,194,304 halfs
  unsigned short* Qb_v = ws + 4194304;
  unsigned short* K_v  = ws + 8388608;             // 5,242,880
  unsigned short* V_vT = ws + 13631488;
  unsigned short* Qa_t = ws + 18874368;            // 1,048,576
  unsigned short* Qb_t = ws + 19922944;
  unsigned short* K_t  = ws + 20971520;            // 5,242,880
  unsigned short* V_tT = ws + 26214400;            // end 31,457,280
  unsigned short* Xv_h = ws + 31457280;            // 4,194,304 (dead after proj)
  unsigned short* Xt_h = ws + 35651584;            // 1,048,576
  unsigned short* Wh   = ws + 36700160;            // 12 MEG -> end 49,283,072
  float* kbias = (float*)(ws + 31457280);          // reuses Xv_h AFTER proj

  const size_t need = (size_t)49283072 * 2;
  const bool use_h = ws_size >= need;

  if (use_h) {
    CvtArgs ca;
    ca.d[0] = CvtDesc{vid, Xv_h, 4194304 / 8};
    ca.d[1] = CvtDesc{txt, Xt_h, 1048576 / 8};
    for (int s = 0; s < 4; ++s)
      for (int j = 0; j < 3; ++j)
        ca.d[2 + s * 3 + j] = CvtDesc{Wsrc[s] + j * DD, Wh + (s * 3 + j) * MEG, DD / 8};
    cvt_fp16<<<dim3(256, 14), dim3(256), 0, stream>>>(ca);

    ProjArgsH pa;
    auto set = [&](int i, const unsigned short* X, int wi, const float* Bv,
                   unsigned short* dst, int M, int lxsh, int Ld, int soff, int mode) {
      pa.d[i] = ProjDescH{X, Wh + wi * MEG, Bv, dst, M, lxsh, Ld, soff, mode};
    };
    set(0,  Xv_h, 0,  Bsrc[0],          Qa_v, 4096, 10, 1024, 0,    0);
    set(1,  Xv_h, 1,  Bsrc[0] + Dm,     K_v,  4096, 10, 1280, 0,    0);
    set(2,  Xv_h, 2,  Bsrc[0] + 2 * Dm, V_vT, 4096, 10, 1280, 0,    1);
    set(3,  Xv_h, 3,  Bsrc[1],          Qb_v, 4096, 10, 1024, 0,    0);
    set(4,  Xt_h, 4,  Bsrc[1] + Dm,     K_v,  1024, 8,  1280, 1024, 0);
    set(5,  Xt_h, 5,  Bsrc[1] + 2 * Dm, V_vT, 1024, 8,  1280, 1024, 1);
    set(6,  Xt_h, 6,  Bsrc[2],          Qa_t, 1024, 8,  256,  0,    0);
    set(7,  Xv_h, 7,  Bsrc[2] + Dm,     K_t,  4096, 10, 1280, 0,    0);
    set(8,  Xv_h, 8,  Bsrc[2] + 2 * Dm, V_tT, 4096, 10, 1280, 0,    1);
    set(9,  Xt_h, 9,  Bsrc[3],          Qb_t, 1024, 8,  256,  0,    0);
    set(10, Xt_h, 10, Bsrc[3] + Dm,     K_t,  1024, 8,  1280, 1024, 0);
    set(11, Xt_h, 11, Bsrc[3] + 2 * Dm, V_tT, 1024, 8,  1280, 1024, 1);

    proj_gemm_h<<<dim3(8, 32, 12), dim3(256), 0, stream>>>(pa);
  } else {
    ProjArgs pa;
    auto set = [&](int i, const float* X, const float* W, const float* Bv,
                   unsigned short* dst, int M, int lxsh, int Ld, int soff, int mode) {
      pa.d[i] = ProjDesc{X, W, Bv, dst, M, lxsh, Ld, soff, mode};
    };
    set(0,  vid, Wsrc[0],          Bsrc[0],          Qa_v, 4096, 10, 1024, 0,    0);
    set(1,  vid, Wsrc[0] + DD,     Bsrc[0] + Dm,     K_v,  4096, 10, 1280, 0,    0);
    set(2,  vid, Wsrc[0] + 2 * DD, Bsrc[0] + 2 * Dm, V_vT, 4096, 10, 1280, 0,    1);
    set(3,  vid, Wsrc[1],          Bsrc[1],          Qb_v, 4096, 10, 1024, 0,    0);
    set(4,  txt, Wsrc[1] + DD,     Bsrc[1] + Dm,     K_v,  1024, 8,  1280, 1024, 0);
    set(5,  txt, Wsrc[1] + 2 * DD, Bsrc[1] + 2 * Dm, V_vT, 1024, 8,  1280, 1024, 1);
    set(6,  txt, Wsrc[2],          Bsrc[2],          Qa_t, 1024, 8,  256,  0,    0);
    set(7,  vid, Wsrc[2] + DD,     Bsrc[2] + Dm,     K_t,  4096, 10, 1280, 0,    0);
    set(8,  vid, Wsrc[2] + 2 * DD, Bsrc[2] + 2 * Dm, V_tT, 4096, 10, 1280, 0,    1);
    set(9,  txt, Wsrc[3],          Bsrc[3],          Qb_t, 1024, 8,  256,  0,    0);
    set(10, txt, Wsrc[3] + DD,     Bsrc[3] + Dm,     K_t,  1024, 8,  1280, 1024, 0);
    set(11, txt, Wsrc[3] + 2 * DD, Bsrc[3] + 2 * Dm, V_tT, 1024, 8,  1280, 1024, 1);

    proj_gemm_f32<<<dim3(8, 32, 12), dim3(256), 0, stream>>>(pa);
  }

  make_kbias<<<dim3(5, 4), dim3(256), 0, stream>>>(vmask, tmask, kbias);

  float* out_v = (float*)d_out;
  float* out_t = out_v + 4 * 1024 * 1024;
  attn_flash4<<<dim3(80, 64), dim3(256), 0, stream>>>(
      Qa_v, Qb_v, K_v, V_vT, Qa_t, Qb_t, K_t, V_tT,
      vmask, tmask, kbias, out_v, out_t);
}

// Round 10
// 339.185 us; speedup vs baseline: 1.4728x; 1.4728x over previous
//
#include <hip/hip_runtime.h>

// ---------------------------------------------------------------------------
// SegFormerXAttention on MI355X (gfx950)
//  B=4, Lv=1024, Lt=256, D=1024, H=16, DH=64, L=1280. fp32 in/out, int32 masks.
//  r10: attention is L2-line-traffic bound (r7/r9 durations match 6.7/11 TB
//  of 128B-line fetches at 34.5 TB/s; V^T rows are 2560B-strided so every
//  16B fragment burned a full line). Fix: tiled layouts written by the proj
//  epilogue so every line is 100% used:
//    K: [bh][k/16][dhhalf][key16][qdchunk]  (1KB contiguous per b128 instr)
//    V: [bh][k/32][dh=64][32keys, permuted] (half8 = sub0|sub1 half4 pair)
//  Attention math identical to r9 (S^T form, register PV, split-K 4x320).
// ---------------------------------------------------------------------------

typedef __attribute__((ext_vector_type(8))) _Float16  half8;    // 8 x f16
typedef __attribute__((ext_vector_type(4))) _Float16  half4;    // 4 x f16
typedef __attribute__((ext_vector_type(4))) float     f32x4;
typedef __attribute__((ext_vector_type(4))) unsigned int uint4v;
typedef __attribute__((ext_vector_type(2))) unsigned int uint2v;

#define MFMA_F16   __builtin_amdgcn_mfma_f32_16x16x32_f16
#define MFMA16_F16 __builtin_amdgcn_mfma_f32_16x16x16f16

static __device__ __forceinline__ unsigned short f_to_f16u(float f) {
  _Float16 h = (_Float16)f;
  return __builtin_bit_cast(unsigned short, h);
}

#define GLOAD_LDS16(g, l)                                            \
  __builtin_amdgcn_global_load_lds(                                  \
      (const __attribute__((address_space(1))) void*)(g),            \
      (__attribute__((address_space(3))) void*)(l), 16, 0, 0)

// ---------------------------------------------------------------------------
// Pre-pass: fp32 -> fp16 elementwise
// ---------------------------------------------------------------------------
struct CvtDesc { const float* src; unsigned short* dst; int n8; };
struct CvtArgs { CvtDesc d[14]; };

__global__ __launch_bounds__(256) void cvt_fp16(CvtArgs ca) {
  const CvtDesc dd = ca.d[blockIdx.y];
  const int stride = gridDim.x * blockDim.x;
  for (int i = blockIdx.x * blockDim.x + threadIdx.x; i < dd.n8; i += stride) {
    const f32x4 a = ((const f32x4*)dd.src)[i * 2];
    const f32x4 b = ((const f32x4*)dd.src)[i * 2 + 1];
    half8 h;
    h[0] = (_Float16)a[0]; h[1] = (_Float16)a[1];
    h[2] = (_Float16)a[2]; h[3] = (_Float16)a[3];
    h[4] = (_Float16)b[0]; h[5] = (_Float16)b[1];
    h[6] = (_Float16)b[2]; h[7] = (_Float16)b[3];
    ((half8*)dd.dst)[i] = h;
  }
}

// key-mask bias: kb[b][k] = mask ? 0 : -10000  (reuses dead Xv_h region)
__global__ __launch_bounds__(256) void make_kbias(
    const int* __restrict__ vmask, const int* __restrict__ tmask,
    float* __restrict__ kb) {
  const int b = blockIdx.y;
  const int k = blockIdx.x * 256 + threadIdx.x;
  if (k >= 1280) return;
  const int m = (k < 1024) ? vmask[b * 1024 + k] : tmask[b * 256 + k - 1024];
  kb[b * 1280 + k] = m ? 0.0f : -10000.0f;
}

// ---------------------------------------------------------------------------
// Shared GEMM epilogue copy-out. Cs layout: row*136 + swizzled 8-half chunks.
//  mode 0 (Q): dst[((b*16+h)*Ld + soff + l)*64 + dh]   (linear, seq-major)
//  mode 2 (K): dst[bh*81920 + (k>>4)*1024 + (dh>>5)*512 + (k&15)*32
//                   + ((dh>>3)&3)*8 + (dh&7)]           (1KB-contig tiles)
//  mode 1 (V): dst[bh*81920 + (k>>5)*2048 + dh*32 + p], tile positions p
//              permuted: p = q*8+j holds key 4q + (j&3) + 16*(j>>2)
// ---------------------------------------------------------------------------
static __device__ __forceinline__ void copy_out_tile(
    const unsigned short* Cs, unsigned short* dst, int tid,
    int b, int l0, int h0, int Ld, int soff, int mode) {
  for (int i = 0; i < 8; ++i) {
    const int c     = i * 256 + tid;
    const int major = c >> 4;                // mode0/2: l-local; mode1: dh-local
    const int kc    = c & 15;
    if (mode == 1) {
      const int base = (kc >> 2) * 32 + (kc & 3) * 4;
      const int sw   = major & 7;
      const int o1   = major * 136 + (((base >> 3) ^ sw) << 3) + (base & 7);
      const int b2   = base + 16;
      const int o2   = major * 136 + (((b2 >> 3) ^ sw) << 3) + (b2 & 7);
      const uint2v lo = *(const uint2v*)&Cs[o1];
      const uint2v hi = *(const uint2v*)&Cs[o2];
      uint4v val; val[0] = lo[0]; val[1] = lo[1]; val[2] = hi[0]; val[3] = hi[1];
      const int hh = h0 + (major >> 6);
      const int dh = major & 63;
      const int k  = soff + l0 + (kc >> 2) * 32;
      const size_t el = (size_t)(b * 16 + hh) * 81920 + (size_t)(k >> 5) * 2048 +
                        dh * 32 + (kc & 3) * 8;
      *(uint4v*)(dst + el) = val;
    } else {
      const uint4v val =
          *(const uint4v*)&Cs[major * 136 + ((kc ^ (major & 7)) << 3)];
      if (mode == 0) {
        const size_t el =
            ((size_t)(b * 16 + h0 + (kc >> 3)) * Ld + soff + l0 + major) * 64 +
            (kc & 7) * 8;
        *(uint4v*)(dst + el) = val;
      } else {  // mode 2
        const int k   = soff + l0 + major;
        const int dh0 = (kc & 7) * 8;
        const size_t el = (size_t)(b * 16 + h0 + (kc >> 3)) * 81920 +
                          (size_t)(k >> 4) * 1024 + (dh0 >> 5) * 512 +
                          (k & 15) * 32 + ((dh0 >> 3) & 3) * 8;
        *(uint4v*)(dst + el) = val;
      }
    }
  }
}

// ---------------------------------------------------------------------------
// Projection GEMM (fp16 inputs)
// ---------------------------------------------------------------------------
struct ProjDescH {
  const unsigned short* X;
  const unsigned short* W;
  const float* Bv;
  unsigned short* dst;
  int M, lxsh, Ld, soff, mode;
};
struct ProjArgsH { ProjDescH d[12]; };

__global__ __launch_bounds__(256) void proj_gemm_h(ProjArgsH pa) {
  const ProjDescH dd = pa.d[blockIdx.z];
  const int m0 = blockIdx.y * 128;
  if (m0 >= dd.M) return;
  const int n0 = blockIdx.x * 128;

  __shared__ __align__(16) unsigned char smem[34816];
  unsigned short* As = (unsigned short*)smem;
  unsigned short* Bs = As + 4096;
  unsigned short* Cs = (unsigned short*)smem;

  const int tid  = threadIdx.x;
  const int lane = tid & 63;
  const int w    = tid >> 6;
  const int wr   = (w >> 1) * 64;
  const int wc   = (w & 1) * 64;
  const int ql   = lane & 15;
  const int qd   = lane >> 4;

  f32x4 acc[4][4];
  for (int i = 0; i < 4; ++i)
    for (int j = 0; j < 4; ++j) acc[i][j] = (f32x4)(0.0f);

  const unsigned short* Xg = dd.X + (size_t)m0 * 1024;
  const unsigned short* Wg = dd.W + (size_t)n0 * 1024;

  for (int k0 = 0; k0 < 1024; k0 += 32) {
    __syncthreads();
    for (int half = 0; half < 2; ++half) {
      const int cb  = w * 128 + half * 64;
      const int c   = cb + lane;
      const int row = c >> 2;
      const int kcg = (c & 3) ^ (row & 3);
      GLOAD_LDS16(Xg + row * 1024 + k0 + kcg * 8, As + cb * 8);
      GLOAD_LDS16(Wg + row * 1024 + k0 + kcg * 8, Bs + cb * 8);
    }
    __syncthreads();

    half8 af[4], bf[4];
    for (int mt = 0; mt < 4; ++mt) {
      const int row = wr + mt * 16 + ql;
      af[mt] = *(const half8*)&As[row * 32 + ((qd ^ (row & 3)) << 3)];
    }
    for (int nt = 0; nt < 4; ++nt) {
      const int row = wc + nt * 16 + ql;
      bf[nt] = *(const half8*)&Bs[row * 32 + ((qd ^ (row & 3)) << 3)];
    }
    for (int mt = 0; mt < 4; ++mt)
      for (int nt = 0; nt < 4; ++nt)
        acc[mt][nt] = MFMA_F16(af[mt], bf[nt], acc[mt][nt], 0, 0, 0);
  }

  float bv[4];
  for (int nt = 0; nt < 4; ++nt)
    bv[nt] = dd.Bv[n0 + wc + nt * 16 + ql];

  __syncthreads();

  for (int mt = 0; mt < 4; ++mt) {
    for (int nt = 0; nt < 4; ++nt) {
      const int nl = wc + nt * 16 + ql;
      for (int r = 0; r < 4; ++r) {
        const int ml = wr + mt * 16 + qd * 4 + r;
        const int row = dd.mode == 1 ? nl : ml;
        const int col = dd.mode == 1 ? ml : nl;
        const float v = acc[mt][nt][r] + bv[nt];
        Cs[row * 136 + (((col >> 3) ^ (row & 7)) << 3) + (col & 7)] = f_to_f16u(v);
      }
    }
  }
  __syncthreads();

  copy_out_tile(Cs, dd.dst, tid, m0 >> dd.lxsh, m0 & ((1 << dd.lxsh) - 1),
                n0 >> 6, dd.Ld, dd.soff, dd.mode);
}

// ---------------------------------------------------------------------------
// Fallback fp32-input GEMM for small ws_size (same output layouts)
// ---------------------------------------------------------------------------
struct ProjDesc {
  const float* X;
  const float* W;
  const float* Bv;
  unsigned short* dst;
  int M, lxsh, Ld, soff, mode;
};
struct ProjArgs { ProjDesc d[12]; };

static __device__ __forceinline__ half8 cvt8sw(const float* base, int row, int g0) {
  const int sw = row & 7;
  const f32x4 a = *(const f32x4*)(base + (row * 8 + (g0 ^ sw)) * 4);
  const f32x4 b = *(const f32x4*)(base + (row * 8 + ((g0 + 1) ^ sw)) * 4);
  half8 h;
  h[0] = (_Float16)a[0]; h[1] = (_Float16)a[1];
  h[2] = (_Float16)a[2]; h[3] = (_Float16)a[3];
  h[4] = (_Float16)b[0]; h[5] = (_Float16)b[1];
  h[6] = (_Float16)b[2]; h[7] = (_Float16)b[3];
  return h;
}

__global__ __launch_bounds__(256) void proj_gemm_f32(ProjArgs pa) {
  const ProjDesc dd = pa.d[blockIdx.z];
  const int m0 = blockIdx.y * 128;
  if (m0 >= dd.M) return;
  const int n0 = blockIdx.x * 128;

  __shared__ __align__(16) unsigned char smem[34816];
  float* As = (float*)smem;
  float* Bs = As + 4096;
  unsigned short* Cs = (unsigned short*)smem;

  const int tid  = threadIdx.x;
  const int lane = tid & 63;
  const int w    = tid >> 6;
  const int wr   = (w >> 1) * 64;
  const int wc   = (w & 1) * 64;
  const int ql   = lane & 15;
  const int qd   = lane >> 4;

  f32x4 acc[4][4];
  for (int i = 0; i < 4; ++i)
    for (int j = 0; j < 4; ++j) acc[i][j] = (f32x4)(0.0f);

  const float* Xg = dd.X + (size_t)m0 * 1024;
  const float* Wg = dd.W + (size_t)n0 * 1024;

  for (int k0 = 0; k0 < 1024; k0 += 32) {
    __syncthreads();
    for (int j = 0; j < 4; ++j) {
      const int cb  = (j * 4 + w) * 64;
      const int c   = cb + lane;
      const int row = c >> 3;
      const int kcg = (c & 7) ^ (row & 7);
      GLOAD_LDS16(Xg + row * 1024 + k0 + kcg * 4, As + cb * 4);
      GLOAD_LDS16(Wg + row * 1024 + k0 + kcg * 4, Bs + cb * 4);
    }
    __syncthreads();

    half8 af[4], bf[4];
    for (int mt = 0; mt < 4; ++mt)
      af[mt] = cvt8sw(As, wr + mt * 16 + ql, qd * 2);
    for (int nt = 0; nt < 4; ++nt)
      bf[nt] = cvt8sw(Bs, wc + nt * 16 + ql, qd * 2);
    for (int mt = 0; mt < 4; ++mt)
      for (int nt = 0; nt < 4; ++nt)
        acc[mt][nt] = MFMA_F16(af[mt], bf[nt], acc[mt][nt], 0, 0, 0);
  }

  float bv[4];
  for (int nt = 0; nt < 4; ++nt)
    bv[nt] = dd.Bv[n0 + wc + nt * 16 + ql];

  __syncthreads();

  for (int mt = 0; mt < 4; ++mt) {
    for (int nt = 0; nt < 4; ++nt) {
      const int nl = wc + nt * 16 + ql;
      for (int r = 0; r < 4; ++r) {
        const int ml = wr + mt * 16 + qd * 4 + r;
        const int row = dd.mode == 1 ? nl : ml;
        const int col = dd.mode == 1 ? ml : nl;
        const float v = acc[mt][nt][r] + bv[nt];
        Cs[row * 136 + (((col >> 3) ^ (row & 7)) << 3) + (col & 7)] = f_to_f16u(v);
      }
    }
  }
  __syncthreads();

  copy_out_tile(Cs, dd.dst, tid, m0 >> dd.lxsh, m0 & ((1 << dd.lxsh) - 1),
                n0 >> 6, dd.Ld, dd.soff, dd.mode);
}

// ---------------------------------------------------------------------------
// Split-K flash attention, S^T form, tiled K/V loads (full-line utilization).
// ---------------------------------------------------------------------------
__global__ __launch_bounds__(256) void attn_flash5(
    const unsigned short* __restrict__ Qa_v, const unsigned short* __restrict__ Qb_v,
    const unsigned short* __restrict__ K_v,  const unsigned short* __restrict__ V_vT,
    const unsigned short* __restrict__ Qa_t, const unsigned short* __restrict__ Qb_t,
    const unsigned short* __restrict__ K_t,  const unsigned short* __restrict__ V_tT,
    const int* __restrict__ vmask, const int* __restrict__ tmask,
    const float* __restrict__ kbias,
    float* __restrict__ out_v, float* __restrict__ out_t) {
  __shared__ __align__(16) float oM[4 * 1088];   // o[w][q=ql][68]
  __shared__ float mlM[128];                     // ml[w][{m,l}][16]

  const bool vside = blockIdx.x < 64;
  const int  qb    = vside ? blockIdx.x : blockIdx.x - 64;
  const int  Lq    = vside ? 1024 : 256;
  const unsigned short* Qa = vside ? Qa_v : Qa_t;
  const unsigned short* Qb = vside ? Qb_v : Qb_t;
  const unsigned short* K  = vside ? K_v  : K_t;
  const unsigned short* VT = vside ? V_vT : V_tT;
  const int* mq  = vside ? vmask : tmask;
  float*     out = vside ? out_v : out_t;

  const int bh = blockIdx.y;
  const int b  = bh >> 4;
  const int h  = bh & 15;
  const int w    = threadIdx.x >> 6;
  const int lane = threadIdx.x & 63;
  const int ql = lane & 15, qd = lane >> 4;
  const int q0 = qb * 16;

  const unsigned short* Qab = Qa + ((size_t)bh * Lq + q0) * 64;
  const unsigned short* Qbb = Qb + ((size_t)bh * Lq + q0) * 64;
  half8 aA[2], aB[2];
  for (int ks = 0; ks < 2; ++ks) {
    aA[ks] = *(const half8*)&Qab[ql * 64 + ks * 32 + qd * 8];
    aB[ks] = *(const half8*)&Qbb[ql * 64 + ks * 32 + qd * 8];
  }
  const int mqs = mq[b * Lq + q0 + ql];

  float m = -1e30f, l = 0.0f;
  f32x4 o[4];
  for (int nt = 0; nt < 4; ++nt) o[nt] = (f32x4)(0.0f);

  const unsigned short* Kb = K  + (size_t)bh * 81920;
  const unsigned short* Vb = VT + (size_t)bh * 81920;
  const float* kbb = kbias + b * 1280;

  const int kw0 = w * 320;
  for (int k0 = kw0; k0 < kw0 + 320; k0 += 32) {
    const bool vidp = (k0 < 1024);

    // V tile loads first (independent of softmax chain; 8 full lines each)
    const unsigned short* Vtile = Vb + (size_t)(k0 >> 5) * 2048;
    half8 vv[4];
    for (int nt = 0; nt < 4; ++nt)
      vv[nt] = *(const half8*)&Vtile[(nt * 16 + ql) * 32 + qd * 8];

    f32x4 sv[2];
    for (int sub = 0; sub < 2; ++sub) {
      const int kb = k0 + sub * 16;
      f32x4 S = *(const f32x4*)&kbb[kb + qd * 4];
      const unsigned short* Ktile = Kb + (size_t)(kb >> 4) * 1024;
      const half8 kf0 = *(const half8*)&Ktile[ql * 32 + qd * 8];
      const half8 kf1 = *(const half8*)&Ktile[512 + ql * 32 + qd * 8];
      if (vidp) { S = MFMA_F16(kf0, aA[0], S, 0, 0, 0); S = MFMA_F16(kf1, aA[1], S, 0, 0, 0); }
      else      { S = MFMA_F16(kf0, aB[0], S, 0, 0, 0); S = MFMA_F16(kf1, aB[1], S, 0, 0, 0); }
      for (int r = 0; r < 4; ++r)
        sv[sub][r] = mqs ? S[r] : -10000.0f;
    }

    float bm = fmaxf(fmaxf(fmaxf(sv[0][0], sv[0][1]), fmaxf(sv[0][2], sv[0][3])),
                     fmaxf(fmaxf(sv[1][0], sv[1][1]), fmaxf(sv[1][2], sv[1][3])));
    bm = fmaxf(bm, __shfl_xor(bm, 16, 64));
    bm = fmaxf(bm, __shfl_xor(bm, 32, 64));
    const float nm = fmaxf(m, bm);
    const float alpha = __expf(m - nm);
    m = nm;
    half4 pv[2];
    float lsum = 0.0f;
    for (int sub = 0; sub < 2; ++sub)
      for (int r = 0; r < 4; ++r) {
        const float p = __expf(sv[sub][r] - m);
        lsum += p;
        pv[sub][r] = (_Float16)p;
      }
    l = l * alpha + lsum;
    for (int nt = 0; nt < 4; ++nt)
      for (int r = 0; r < 4; ++r) o[nt][r] *= alpha;

    for (int nt = 0; nt < 4; ++nt) {
      const half4 vlo = __builtin_shufflevector(vv[nt], vv[nt], 0, 1, 2, 3);
      const half4 vhi = __builtin_shufflevector(vv[nt], vv[nt], 4, 5, 6, 7);
      o[nt] = MFMA16_F16(vlo, pv[0], o[nt], 0, 0, 0);
      o[nt] = MFMA16_F16(vhi, pv[1], o[nt], 0, 0, 0);
    }
  }

  l += __shfl_xor(l, 16, 64);
  l += __shfl_xor(l, 32, 64);

  for (int nt = 0; nt < 4; ++nt)
    for (int r = 0; r < 4; ++r)
      oM[w * 1088 + ql * 68 + nt * 16 + qd * 4 + r] = o[nt][r];
  if (qd == 0) {
    mlM[w * 32 + ql]      = m;
    mlM[w * 32 + 16 + ql] = l;
  }
  __syncthreads();

  const int q  = threadIdx.x >> 4;
  const int d0 = (threadIdx.x & 15) * 4;
  float mw[4], lw[4];
  for (int w2 = 0; w2 < 4; ++w2) {
    mw[w2] = mlM[w2 * 32 + q];
    lw[w2] = mlM[w2 * 32 + 16 + q];
  }
  float ms = fmaxf(fmaxf(mw[0], mw[1]), fmaxf(mw[2], mw[3]));
  float fw[4], ls = 0.0f;
  for (int w2 = 0; w2 < 4; ++w2) {
    fw[w2] = __expf(mw[w2] - ms);
    ls += fw[w2] * lw[w2];
  }
  const float inv = 0.125f / ls;
  f32x4 res;
  for (int j = 0; j < 4; ++j) {
    float a = 0.0f;
    for (int w2 = 0; w2 < 4; ++w2)
      a += fw[w2] * oM[w2 * 1088 + q * 68 + d0 + j];
    res[j] = a * inv;
  }
  *(f32x4*)(out + ((size_t)(b * Lq + q0 + q)) * 1024 + h * 64 + d0) = res;
}

// ---------------------------------------------------------------------------
extern "C" void kernel_launch(void* const* d_in, const int* in_sizes, int n_in,
                              void* d_out, int out_size, void* d_ws, size_t ws_size,
                              hipStream_t stream) {
  const float* vid   = (const float*)d_in[0];
  const int*   vmask = (const int*)d_in[1];
  const float* txt   = (const float*)d_in[2];
  const int*   tmask = (const int*)d_in[3];
  const float* Wsrc[4] = {(const float*)d_in[4], (const float*)d_in[6],
                          (const float*)d_in[8], (const float*)d_in[10]};
  const float* Bsrc[4] = {(const float*)d_in[5], (const float*)d_in[7],
                          (const float*)d_in[9], (const float*)d_in[11]};

  const int DD = 1024 * 1024, Dm = 1024, MEG = 1048576;

  unsigned short* ws = (unsigned short*)d_ws;
  unsigned short* Qa_v = ws;                       // 4,194,304 halfs
  unsigned short* Qb_v = ws + 4194304;
  unsigned short* K_v  = ws + 8388608;             // 5,242,880
  unsigned short* V_vT = ws + 13631488;
  unsigned short* Qa_t = ws + 18874368;            // 1,048,576
  unsigned short* Qb_t = ws + 19922944;
  unsigned short* K_t  = ws + 20971520;            // 5,242,880
  unsigned short* V_tT = ws + 26214400;            // end 31,457,280
  unsigned short* Xv_h = ws + 31457280;            // 4,194,304 (dead after proj)
  unsigned short* Xt_h = ws + 35651584;            // 1,048,576
  unsigned short* Wh   = ws + 36700160;            // 12 MEG -> end 49,283,072
  float* kbias = (float*)(ws + 31457280);          // reuses Xv_h AFTER proj

  const size_t need = (size_t)49283072 * 2;
  const bool use_h = ws_size >= need;

  if (use_h) {
    CvtArgs ca;
    ca.d[0] = CvtDesc{vid, Xv_h, 4194304 / 8};
    ca.d[1] = CvtDesc{txt, Xt_h, 1048576 / 8};
    for (int s = 0; s < 4; ++s)
      for (int j = 0; j < 3; ++j)
        ca.d[2 + s * 3 + j] = CvtDesc{Wsrc[s] + j * DD, Wh + (s * 3 + j) * MEG, DD / 8};
    cvt_fp16<<<dim3(256, 14), dim3(256), 0, stream>>>(ca);

    ProjArgsH pa;
    auto set = [&](int i, const unsigned short* X, int wi, const float* Bv,
                   unsigned short* dst, int M, int lxsh, int Ld, int soff, int mode) {
      pa.d[i] = ProjDescH{X, Wh + wi * MEG, Bv, dst, M, lxsh, Ld, soff, mode};
    };
    //    idx  X     Wi  bias          dst    M     lxsh Ld    soff  mode
    set(0,  Xv_h, 0,  Bsrc[0],          Qa_v, 4096, 10, 1024, 0,    0);
    set(1,  Xv_h, 1,  Bsrc[0] + Dm,     K_v,  4096, 10, 1280, 0,    2);
    set(2,  Xv_h, 2,  Bsrc[0] + 2 * Dm, V_vT, 4096, 10, 1280, 0,    1);
    set(3,  Xv_h, 3,  Bsrc[1],          Qb_v, 4096, 10, 1024, 0,    0);
    set(4,  Xt_h, 4,  Bsrc[1] + Dm,     K_v,  1024, 8,  1280, 1024, 2);
    set(5,  Xt_h, 5,  Bsrc[1] + 2 * Dm, V_vT, 1024, 8,  1280, 1024, 1);
    set(6,  Xt_h, 6,  Bsrc[2],          Qa_t, 1024, 8,  256,  0,    0);
    set(7,  Xv_h, 7,  Bsrc[2] + Dm,     K_t,  4096, 10, 1280, 0,    2);
    set(8,  Xv_h, 8,  Bsrc[2] + 2 * Dm, V_tT, 4096, 10, 1280, 0,    1);
    set(9,  Xt_h, 9,  Bsrc[3],          Qb_t, 1024, 8,  256,  0,    0);
    set(10, Xt_h, 10, Bsrc[3] + Dm,     K_t,  1024, 8,  1280, 1024, 2);
    set(11, Xt_h, 11, Bsrc[3] + 2 * Dm, V_tT, 1024, 8,  1280, 1024, 1);

    proj_gemm_h<<<dim3(8, 32, 12), dim3(256), 0, stream>>>(pa);
  } else {
    ProjArgs pa;
    auto set = [&](int i, const float* X, const float* W, const float* Bv,
                   unsigned short* dst, int M, int lxsh, int Ld, int soff, int mode) {
      pa.d[i] = ProjDesc{X, W, Bv, dst, M, lxsh, Ld, soff, mode};
    };
    set(0,  vid, Wsrc[0],          Bsrc[0],          Qa_v, 4096, 10, 1024, 0,    0);
    set(1,  vid, Wsrc[0] + DD,     Bsrc[0] + Dm,     K_v,  4096, 10, 1280, 0,    2);
    set(2,  vid, Wsrc[0] + 2 * DD, Bsrc[0] + 2 * Dm, V_vT, 4096, 10, 1280, 0,    1);
    set(3,  vid, Wsrc[1],          Bsrc[1],          Qb_v, 4096, 10, 1024, 0,    0);
    set(4,  txt, Wsrc[1] + DD,     Bsrc[1] + Dm,     K_v,  1024, 8,  1280, 1024, 2);
    set(5,  txt, Wsrc[1] + 2 * DD, Bsrc[1] + 2 * Dm, V_vT, 1024, 8,  1280, 1024, 1);
    set(6,  txt, Wsrc[2],          Bsrc[2],          Qa_t, 1024, 8,  256,  0,    0);
    set(7,  vid, Wsrc[2] + DD,     Bsrc[2] + Dm,     K_t,  4096, 10, 1280, 0,    2);
    set(8,  vid, Wsrc[2] + 2 * DD, Bsrc[2] + 2 * Dm, V_tT, 4096, 10, 1280, 0,    1);
    set(9,  txt, Wsrc[3],          Bsrc[3],          Qb_t, 1024, 8,  256,  0,    0);
    set(10, txt, Wsrc[3] + DD,     Bsrc[3] + Dm,     K_t,  1024, 8,  1280, 1024, 2);
    set(11, txt, Wsrc[3] + 2 * DD, Bsrc[3] + 2 * Dm, V_tT, 1024, 8,  1280, 1024, 1);

    proj_gemm_f32<<<dim3(8, 32, 12), dim3(256), 0, stream>>>(pa);
  }

  make_kbias<<<dim3(5, 4), dim3(256), 0, stream>>>(vmask, tmask, kbias);

  float* out_v = (float*)d_out;
  float* out_t = out_v + 4 * 1024 * 1024;
  attn_flash5<<<dim3(80, 64), dim3(256), 0, stream>>>(
      Qa_v, Qb_v, K_v, V_vT, Qa_t, Qb_t, K_t, V_tT,
      vmask, tmask, kbias, out_v, out_t);
}